// Round 13
// baseline (290.293 us; speedup 1.0000x reference)
//
#include <hip/hip_runtime.h>

#define H    128
#define WP   130
#define BPF  516           // border pixels per face image
#define TBLN 3096          // 6 * 516
#define NIMG 6144
#define NTASK (6144u * 17u)   // 104448 block-tasks: img*17 + sub

// Face order: back(0), down(1), front(2), left(3), right(4), top(5)
__constant__ int c_R[6][9] = {
  {-1,0,0,  0,1,0,  0,0,-1},
  { 1,0,0,  0,0,-1, 0,1,0 },
  { 1,0,0,  0,1,0,  0,0,1 },
  { 0,0,1,  0,1,0, -1,0,0 },
  { 0,0,-1, 0,1,0,  1,0,0 },
  { 1,0,0,  0,0,1,  0,-1,0},
};
// NEIGHBORS[face][side], side order: up(0), down(1), left(2), right(3)
__constant__ int c_conn[6][4] = {
  {5,1,4,3}, {2,0,3,4}, {5,1,3,4}, {5,1,0,2}, {5,1,2,0}, {0,2,3,4},
};

#define INV_FP (65.0f / 4128.0f)

// ---------- kernel A: build border table (3096 entries) ------------------
__global__ void __launch_bounds__(256)
border_table_kernel(int* __restrict__ tb_face, int4* __restrict__ tb_idx,
                    float4* __restrict__ tb_w) {
  int t = blockIdx.x * 256 + threadIdx.x;
  if (t >= TBLN) return;
  int face = t / BPF;
  int k    = t - face * BPF;

  int r, c;
  if (k < 130)      { r = 0;        c = k; }
  else if (k < 260) { r = WP - 1;   c = k - 130; }
  else if (k < 388) { r = k - 259;  c = 0; }
  else              { r = k - 387;  c = WP - 1; }

  int fs = -1;
  int4  idx = make_int4(0, 0, 0, 0);
  float4 w  = make_float4(0.f, 0.f, 0.f, 0.f);

  int cand[2]; int nc = 0;
  if (c == WP - 1) cand[nc++] = 3;
  if (c == 0)      cand[nc++] = 2;
  if (r == WP - 1) cand[nc++] = 1;
  if (r == 0)      cand[nc++] = 0;

  float uc = ((float)c - 64.5f) * INV_FP;
  float ur = ((float)r - 64.5f) * INV_FP;

  for (int kk = 0; kk < nc; ++kk) {
    int s  = cand[kk];
    int cf = c_conn[face][s];
    const int* Rc = c_R[cf];
    const int* Rf = c_R[face];
    float g[3];
    #pragma unroll
    for (int i = 0; i < 3; ++i) {
      float acc = 0.0f;
      #pragma unroll
      for (int j = 0; j < 3; ++j) {
        int rr = Rc[i*3+0]*Rf[j*3+0] + Rc[i*3+1]*Rf[j*3+1] + Rc[i*3+2]*Rf[j*3+2];
        float dj = (j == 0) ? uc : (j == 1) ? ur : 1.0f;
        acc += (float)rr * dj;
      }
      g[i] = acc;
    }
    float x = g[0] / g[2];
    float y = g[1] / g[2];
    if (fabsf(x) <= 1.01f && fabsf(y) <= 1.01f) {
      x = fminf(fmaxf(x, -1.0f), 1.0f);
      y = fminf(fmaxf(y, -1.0f), 1.0f);
      float xp = (x + 1.0f) * 0.5f * (float)(H - 1);
      float yp = (y + 1.0f) * 0.5f * (float)(H - 1);
      float x0 = floorf(xp), y0 = floorf(yp);
      float wx = xp - x0,    wy = yp - y0;
      int x0i = min(max((int)x0, 0), H - 1);
      int x1i = min(x0i + 1, H - 1);
      int y0i = min(max((int)y0, 0), H - 1);
      int y1i = min(y0i + 1, H - 1);
      fs  = cf;
      idx = make_int4(y0i * H + x0i, y0i * H + x1i, y1i * H + x0i, y1i * H + x1i);
      w   = make_float4((1.f - wx) * (1.f - wy), wx * (1.f - wy),
                        (1.f - wx) * wy,         wx * wy);
      break;
    }
  }
  tb_face[t] = fs;
  tb_idx[t]  = idx;
  tb_w[t]    = w;
}

// ---------- kernel B: persistent-grid fused bulk + edge ------------------
// Task t = img*17 + sub (R7's exact dispatch order). sub 0..15 = bulk
// (8 half-rows per block via 32-lane groups, shuffle-neighbor, 1 dense 16B
// load + 1 dense 16B store per output quad); sub 16 = edge (257 quads via
// verified border table). 2048 persistent blocks x 256 threads; block b
// processes tasks b, b+2048, ... (51 iters) -> no block churn, loads of
// task i+1 overlap shuffle/store waits of task i. Bodies byte-identical
// to R7's verified fused_kernel.
__global__ void __launch_bounds__(256)
persist_kernel(const float* __restrict__ in, float4* __restrict__ out4,
               const int* __restrict__ tb_face,
               const int4* __restrict__ tb_idx,
               const float4* __restrict__ tb_w) {
  const unsigned u = threadIdx.x;

  for (unsigned t = blockIdx.x; t < NTASK; t += gridDim.x) {
    unsigned img = t / 17u;                 // magic-mul
    unsigned sub = t - img * 17u;

    if (sub < 16u) {
      // ---- bulk ----
      unsigned hh = (sub << 3) + (u >> 5);  // half index 0..127
      unsigned l  = u & 31u;
      unsigned g  = hh + 1u;                // global half 1..128
      unsigned m  = g >> 1;                 // row-pair 0..64
      unsigned h  = g & 1u;                 // 1 = odd row of pair

      const float4* base = (const float4*)in + ((size_t)img << 12);
      float4 A = base[(hh << 5) + l];
      float bx0 = __shfl_down(A.x, 1, 32);
      float by0 = __shfl_down(A.y, 1, 32);
      float bz0 = __shfl_down(A.z, 1, 32);

      float4 o = h ? make_float4(A.y, A.z, A.w, bx0)
                   : make_float4(A.w, bx0, by0, bz0);
      if (l < 31u)
        out4[(size_t)img * 4225u + 65u * m + 1u + (h << 5) + l] = o;
    } else {
      // ---- edge: 257 quads for this image ----
      unsigned n    = img >> 8;
      unsigned ch   = img & 255u;
      unsigned rep  = n / 6u;
      unsigned face = n - rep * 6u;

      for (unsigned k = u; k < 257u; k += 256u) {
        unsigned qk;
        if (k < 33u)       qk = k;                 // pair 0: q 0..32
        else if (k == 33u) qk = 64u;               // pair 0: q 64
        else if (k == 34u) qk = 4160u;             // pair 64: q 0
        else if (k < 68u)  qk = 4192u + (k - 35u); // pair 64: q 32..64
        else {
          unsigned jj = k - 68u;                   // 0..188
          unsigned mm = 1u + jj / 3u;              // 1..63
          unsigned w  = jj - 3u * (jj / 3u);       // 0,1,2
          qk = 65u * mm + ((w == 0u) ? 0u : (w == 1u) ? 32u : 64u);
        }

        unsigned p = qk << 2;
        unsigned r = p / 130u;
        unsigned c = p - r * 130u;
        float vals[4];
        #pragma unroll
        for (int e = 0; e < 4; ++e) {
          float v;
          if ((r - 1u) < 128u && (c - 1u) < 128u) {
            v = in[((size_t)img << 14) + ((r - 1u) << 7) + (c - 1u)];
          } else {
            unsigned tk = (r == 0u)   ? c
                        : (r == 129u) ? (130u + c)
                        : (c == 0u)   ? (259u + r)
                        :               (387u + r);
            unsigned ti = face * (unsigned)BPF + tk;
            int fs = tb_face[ti];
            v = 0.0f;
            if (fs >= 0) {
              int4   id = tb_idx[ti];
              float4 w  = tb_w[ti];
              const float* s = in +
                  ((size_t)(((rep * 6u + (unsigned)fs) << 8) + ch) << 14);
              v = w.x * s[id.x] + w.y * s[id.y] + w.z * s[id.z] + w.w * s[id.w];
            }
          }
          vals[e] = v;
          if (++c == 130u) { c = 0u; ++r; }
        }
        out4[(size_t)img * 4225u + qk] =
            make_float4(vals[0], vals[1], vals[2], vals[3]);
      }
    }
  }
}

// ---------- fallback: round-2 simple kernels ------------------------------
__global__ void __launch_bounds__(256)
interior_kernel(const float4* __restrict__ in4, float* __restrict__ out) {
  unsigned t = blockIdx.x * 256u + threadIdx.x;
  unsigned c4  = t & 31u;
  unsigned r   = (t >> 5) & 127u;
  unsigned img = t >> 12;
  float4 v = in4[t];
  unsigned o = img * 16900u + (r + 1u) * 130u + 1u + (c4 << 2);
  out[o] = v.x; out[o + 1] = v.y; out[o + 2] = v.z; out[o + 3] = v.w;
}

__global__ void __launch_bounds__(256)
border_kernel(const float* __restrict__ in, float* __restrict__ out) {
  unsigned tid = blockIdx.x * 256u + threadIdx.x;
  const unsigned total = 6144u * 516u;
  if (tid >= total) return;
  unsigned img = tid / 516u;
  unsigned k   = tid - img * 516u;
  int r, c;
  if (k < 130u)      { r = 0;               c = (int)k; }
  else if (k < 260u) { r = WP - 1;          c = (int)(k - 130u); }
  else if (k < 388u) { r = (int)(k - 259u); c = 0; }
  else               { r = (int)(k - 387u); c = WP - 1; }
  int n = (int)(img >> 8), ch = (int)(img & 255u);
  int face = n % 6, rep = n / 6;
  float v = 0.0f;
  int cand[2]; int nc = 0;
  if (c == WP - 1) cand[nc++] = 3;
  if (c == 0)      cand[nc++] = 2;
  if (r == WP - 1) cand[nc++] = 1;
  if (r == 0)      cand[nc++] = 0;
  float uc = ((float)c - 64.5f) * INV_FP;
  float ur = ((float)r - 64.5f) * INV_FP;
  for (int kk = 0; kk < nc; ++kk) {
    int s = cand[kk], cf = c_conn[face][s];
    const int* Rc = c_R[cf]; const int* Rf = c_R[face];
    float g[3];
    #pragma unroll
    for (int i = 0; i < 3; ++i) {
      float acc = 0.0f;
      #pragma unroll
      for (int j = 0; j < 3; ++j) {
        int rr = Rc[i*3+0]*Rf[j*3+0] + Rc[i*3+1]*Rf[j*3+1] + Rc[i*3+2]*Rf[j*3+2];
        float dj = (j == 0) ? uc : (j == 1) ? ur : 1.0f;
        acc += (float)rr * dj;
      }
      g[i] = acc;
    }
    float x = g[0] / g[2], y = g[1] / g[2];
    if (fabsf(x) <= 1.01f && fabsf(y) <= 1.01f) {
      x = fminf(fmaxf(x, -1.0f), 1.0f);
      y = fminf(fmaxf(y, -1.0f), 1.0f);
      const float* src = in + ((size_t)((rep * 6 + cf) * 256 + ch)) * H * H;
      float xp = (x + 1.0f) * 0.5f * (float)(H - 1);
      float yp = (y + 1.0f) * 0.5f * (float)(H - 1);
      float x0 = floorf(xp), y0 = floorf(yp);
      float wx = xp - x0, wy = yp - y0;
      int x0i = min(max((int)x0, 0), H - 1);
      int x1i = min(x0i + 1, H - 1);
      int y0i = min(max((int)y0, 0), H - 1);
      int y1i = min(y0i + 1, H - 1);
      v = src[y0i*H+x0i]*(1.f-wx)*(1.f-wy) + src[y0i*H+x1i]*wx*(1.f-wy)
        + src[y1i*H+x0i]*(1.f-wx)*wy       + src[y1i*H+x1i]*wx*wy;
      break;
    }
  }
  out[(unsigned)img * 16900u + (unsigned)r * 130u + (unsigned)c] = v;
}

extern "C" void kernel_launch(void* const* d_in, const int* in_sizes, int n_in,
                              void* d_out, int out_size, void* d_ws, size_t ws_size,
                              hipStream_t stream) {
  (void)in_sizes; (void)n_in; (void)out_size;
  const float* in = (const float*)d_in[0];
  float* out = (float*)d_out;

  const size_t tbl_bytes = (size_t)TBLN * (4 + 16 + 16);   // 111,456 B

  if (d_ws != nullptr && ws_size >= tbl_bytes) {
    int*    tb_face = (int*)d_ws;
    int4*   tb_idx  = (int4*)(tb_face + TBLN);
    float4* tb_w    = (float4*)(tb_idx + TBLN);
    border_table_kernel<<<(TBLN + 255) / 256, 256, 0, stream>>>(
        tb_face, tb_idx, tb_w);

    persist_kernel<<<2048, 256, 0, stream>>>(in, (float4*)out,
                                             tb_face, tb_idx, tb_w);
  } else {
    interior_kernel<<<98304, 256, 0, stream>>>((const float4*)in, out);
    const unsigned btotal = 6144u * 516u;
    border_kernel<<<(btotal + 255u) / 256u, 256, 0, stream>>>(in, out);
  }
}

// Round 15
// 232.300 us; speedup vs baseline: 1.2496x; 1.2496x over previous
//
#include <hip/hip_runtime.h>

#define H    128
#define WP   130
#define BPF  516           // border pixels per face image
#define TBLN 3096          // 6 * 516
#define NIMG 6144

typedef float f32x4 __attribute__((ext_vector_type(4)));

// Face order: back(0), down(1), front(2), left(3), right(4), top(5)
__constant__ int c_R[6][9] = {
  {-1,0,0,  0,1,0,  0,0,-1},
  { 1,0,0,  0,0,-1, 0,1,0 },
  { 1,0,0,  0,1,0,  0,0,1 },
  { 0,0,1,  0,1,0, -1,0,0 },
  { 0,0,-1, 0,1,0,  1,0,0 },
  { 1,0,0,  0,0,1,  0,-1,0},
};
// NEIGHBORS[face][side], side order: up(0), down(1), left(2), right(3)
__constant__ int c_conn[6][4] = {
  {5,1,4,3}, {2,0,3,4}, {5,1,3,4}, {5,1,0,2}, {5,1,2,0}, {0,2,3,4},
};

#define INV_FP (65.0f / 4128.0f)

// ---------- kernel A: build border table (3096 entries) ------------------
__global__ void __launch_bounds__(256)
border_table_kernel(int* __restrict__ tb_face, int4* __restrict__ tb_idx,
                    float4* __restrict__ tb_w) {
  int t = blockIdx.x * 256 + threadIdx.x;
  if (t >= TBLN) return;
  int face = t / BPF;
  int k    = t - face * BPF;

  int r, c;
  if (k < 130)      { r = 0;        c = k; }
  else if (k < 260) { r = WP - 1;   c = k - 130; }
  else if (k < 388) { r = k - 259;  c = 0; }
  else              { r = k - 387;  c = WP - 1; }

  int fs = -1;
  int4  idx = make_int4(0, 0, 0, 0);
  float4 w  = make_float4(0.f, 0.f, 0.f, 0.f);

  int cand[2]; int nc = 0;
  if (c == WP - 1) cand[nc++] = 3;
  if (c == 0)      cand[nc++] = 2;
  if (r == WP - 1) cand[nc++] = 1;
  if (r == 0)      cand[nc++] = 0;

  float uc = ((float)c - 64.5f) * INV_FP;
  float ur = ((float)r - 64.5f) * INV_FP;

  for (int kk = 0; kk < nc; ++kk) {
    int s  = cand[kk];
    int cf = c_conn[face][s];
    const int* Rc = c_R[cf];
    const int* Rf = c_R[face];
    float g[3];
    #pragma unroll
    for (int i = 0; i < 3; ++i) {
      float acc = 0.0f;
      #pragma unroll
      for (int j = 0; j < 3; ++j) {
        int rr = Rc[i*3+0]*Rf[j*3+0] + Rc[i*3+1]*Rf[j*3+1] + Rc[i*3+2]*Rf[j*3+2];
        float dj = (j == 0) ? uc : (j == 1) ? ur : 1.0f;
        acc += (float)rr * dj;
      }
      g[i] = acc;
    }
    float x = g[0] / g[2];
    float y = g[1] / g[2];
    if (fabsf(x) <= 1.01f && fabsf(y) <= 1.01f) {
      x = fminf(fmaxf(x, -1.0f), 1.0f);
      y = fminf(fmaxf(y, -1.0f), 1.0f);
      float xp = (x + 1.0f) * 0.5f * (float)(H - 1);
      float yp = (y + 1.0f) * 0.5f * (float)(H - 1);
      float x0 = floorf(xp), y0 = floorf(yp);
      float wx = xp - x0,    wy = yp - y0;
      int x0i = min(max((int)x0, 0), H - 1);
      int x1i = min(x0i + 1, H - 1);
      int y0i = min(max((int)y0, 0), H - 1);
      int y1i = min(y0i + 1, H - 1);
      fs  = cf;
      idx = make_int4(y0i * H + x0i, y0i * H + x1i, y1i * H + x0i, y1i * H + x1i);
      w   = make_float4((1.f - wx) * (1.f - wy), wx * (1.f - wy),
                        (1.f - wx) * wy,         wx * wy);
      break;
    }
  }
  tb_face[t] = fs;
  tb_idx[t]  = idx;
  tb_w[t]    = w;
}

// ---------- kernel B: R7 fused bulk + edge, non-temporal variant ---------
// Exact R7 structure (measured best, 240us): grid (17, NIMG), 256 threads.
// bx==0: edge (launched FIRST to remove straggler tail); bx 1..16: bulk.
// Bulk: 32-lane group per half-row; 1 dense nt-load + shfl + 1 dense
// nt-store per output quad. Edge: verified border-table path; nt-stores,
// cached loads (strips are reused across channels via L2/L3).
__global__ void __launch_bounds__(256)
fused_nt_kernel(const float* __restrict__ in, float* __restrict__ out,
                const int* __restrict__ tb_face,
                const int4* __restrict__ tb_idx,
                const float4* __restrict__ tb_w) {
  const unsigned bx  = blockIdx.x;
  const unsigned img = blockIdx.y;
  const unsigned u   = threadIdx.x;
  f32x4* out4 = (f32x4*)out;

  if (bx != 0u) {
    // ---- bulk path ----
    unsigned hh = ((bx - 1u) << 3) + (u >> 5); // half index 0..127
    unsigned l  = u & 31u;                     // lane in 32-group
    unsigned g  = hh + 1u;                     // global half 1..128
    unsigned m  = g >> 1;                      // row-pair 0..64
    unsigned h  = g & 1u;                      // 1 = odd row of pair

    const f32x4* base = (const f32x4*)in + ((size_t)img << 12);
    f32x4 A = __builtin_nontemporal_load(&base[(hh << 5) + l]);
    float bx0 = __shfl_down(A.x, 1, 32);
    float by0 = __shfl_down(A.y, 1, 32);
    float bz0 = __shfl_down(A.z, 1, 32);

    f32x4 o;
    if (h) { o.x = A.y; o.y = A.z; o.z = A.w; o.w = bx0; }
    else   { o.x = A.w; o.y = bx0; o.z = by0; o.w = bz0; }
    if (l < 31u)
      __builtin_nontemporal_store(
          o, &out4[(size_t)img * 4225u + 65u * m + 1u + (h << 5) + l]);
  } else {
    // ---- edge path: 257 quads for this image ----
    unsigned n    = img >> 8;
    unsigned ch   = img & 255u;
    unsigned rep  = n / 6u;
    unsigned face = n - rep * 6u;

    for (unsigned k = u; k < 257u; k += 256u) {
      unsigned qk;
      if (k < 33u)       qk = k;                     // pair 0: q 0..32
      else if (k == 33u) qk = 64u;                   // pair 0: q 64
      else if (k == 34u) qk = 4160u;                 // pair 64: q 0
      else if (k < 68u)  qk = 4192u + (k - 35u);     // pair 64: q 32..64
      else {
        unsigned jj = k - 68u;                       // 0..188
        unsigned mm = 1u + jj / 3u;                  // 1..63
        unsigned w  = jj - 3u * (jj / 3u);           // 0,1,2
        qk = 65u * mm + ((w == 0u) ? 0u : (w == 1u) ? 32u : 64u);
      }

      unsigned p = qk << 2;
      unsigned r = p / 130u;
      unsigned c = p - r * 130u;
      float vals[4];
      #pragma unroll
      for (int e = 0; e < 4; ++e) {
        float v;
        if ((r - 1u) < 128u && (c - 1u) < 128u) {
          v = in[((size_t)img << 14) + ((r - 1u) << 7) + (c - 1u)];
        } else {
          unsigned tk = (r == 0u)   ? c
                      : (r == 129u) ? (130u + c)
                      : (c == 0u)   ? (259u + r)
                      :               (387u + r);
          unsigned ti = face * (unsigned)BPF + tk;
          int fs = tb_face[ti];
          v = 0.0f;
          if (fs >= 0) {
            int4   id = tb_idx[ti];
            float4 w  = tb_w[ti];
            const float* s = in +
                ((size_t)(((rep * 6u + (unsigned)fs) << 8) + ch) << 14);
            v = w.x * s[id.x] + w.y * s[id.y] + w.z * s[id.z] + w.w * s[id.w];
          }
        }
        vals[e] = v;
        if (++c == 130u) { c = 0u; ++r; }
      }
      f32x4 ov; ov.x = vals[0]; ov.y = vals[1]; ov.z = vals[2]; ov.w = vals[3];
      __builtin_nontemporal_store(ov, &out4[(size_t)img * 4225u + qk]);
    }
  }
}

// ---------- fallback: round-2 simple kernels ------------------------------
__global__ void __launch_bounds__(256)
interior_kernel(const float4* __restrict__ in4, float* __restrict__ out) {
  unsigned t = blockIdx.x * 256u + threadIdx.x;
  unsigned c4  = t & 31u;
  unsigned r   = (t >> 5) & 127u;
  unsigned img = t >> 12;
  float4 v = in4[t];
  unsigned o = img * 16900u + (r + 1u) * 130u + 1u + (c4 << 2);
  out[o] = v.x; out[o + 1] = v.y; out[o + 2] = v.z; out[o + 3] = v.w;
}

__global__ void __launch_bounds__(256)
border_kernel(const float* __restrict__ in, float* __restrict__ out) {
  unsigned tid = blockIdx.x * 256u + threadIdx.x;
  const unsigned total = 6144u * 516u;
  if (tid >= total) return;
  unsigned img = tid / 516u;
  unsigned k   = tid - img * 516u;
  int r, c;
  if (k < 130u)      { r = 0;               c = (int)k; }
  else if (k < 260u) { r = WP - 1;          c = (int)(k - 130u); }
  else if (k < 388u) { r = (int)(k - 259u); c = 0; }
  else               { r = (int)(k - 387u); c = WP - 1; }
  int n = (int)(img >> 8), ch = (int)(img & 255u);
  int face = n % 6, rep = n / 6;
  float v = 0.0f;
  int cand[2]; int nc = 0;
  if (c == WP - 1) cand[nc++] = 3;
  if (c == 0)      cand[nc++] = 2;
  if (r == WP - 1) cand[nc++] = 1;
  if (r == 0)      cand[nc++] = 0;
  float uc = ((float)c - 64.5f) * INV_FP;
  float ur = ((float)r - 64.5f) * INV_FP;
  for (int kk = 0; kk < nc; ++kk) {
    int s = cand[kk], cf = c_conn[face][s];
    const int* Rc = c_R[cf]; const int* Rf = c_R[face];
    float g[3];
    #pragma unroll
    for (int i = 0; i < 3; ++i) {
      float acc = 0.0f;
      #pragma unroll
      for (int j = 0; j < 3; ++j) {
        int rr = Rc[i*3+0]*Rf[j*3+0] + Rc[i*3+1]*Rf[j*3+1] + Rc[i*3+2]*Rf[j*3+2];
        float dj = (j == 0) ? uc : (j == 1) ? ur : 1.0f;
        acc += (float)rr * dj;
      }
      g[i] = acc;
    }
    float x = g[0] / g[2], y = g[1] / g[2];
    if (fabsf(x) <= 1.01f && fabsf(y) <= 1.01f) {
      x = fminf(fmaxf(x, -1.0f), 1.0f);
      y = fminf(fmaxf(y, -1.0f), 1.0f);
      const float* src = in + ((size_t)((rep * 6 + cf) * 256 + ch)) * H * H;
      float xp = (x + 1.0f) * 0.5f * (float)(H - 1);
      float yp = (y + 1.0f) * 0.5f * (float)(H - 1);
      float x0 = floorf(xp), y0 = floorf(yp);
      float wx = xp - x0, wy = yp - y0;
      int x0i = min(max((int)x0, 0), H - 1);
      int x1i = min(x0i + 1, H - 1);
      int y0i = min(max((int)y0, 0), H - 1);
      int y1i = min(y0i + 1, H - 1);
      v = src[y0i*H+x0i]*(1.f-wx)*(1.f-wy) + src[y0i*H+x1i]*wx*(1.f-wy)
        + src[y1i*H+x0i]*(1.f-wx)*wy       + src[y1i*H+x1i]*wx*wy;
      break;
    }
  }
  out[(unsigned)img * 16900u + (unsigned)r * 130u + (unsigned)c] = v;
}

extern "C" void kernel_launch(void* const* d_in, const int* in_sizes, int n_in,
                              void* d_out, int out_size, void* d_ws, size_t ws_size,
                              hipStream_t stream) {
  (void)in_sizes; (void)n_in; (void)out_size;
  const float* in = (const float*)d_in[0];
  float* out = (float*)d_out;

  const size_t tbl_bytes = (size_t)TBLN * (4 + 16 + 16);   // 111,456 B

  if (d_ws != nullptr && ws_size >= tbl_bytes) {
    int*    tb_face = (int*)d_ws;
    int4*   tb_idx  = (int4*)(tb_face + TBLN);
    float4* tb_w    = (float4*)(tb_idx + TBLN);
    border_table_kernel<<<(TBLN + 255) / 256, 256, 0, stream>>>(
        tb_face, tb_idx, tb_w);

    dim3 grid(17, NIMG);   // x==0 edge (first), x 1..16 bulk
    fused_nt_kernel<<<grid, 256, 0, stream>>>(in, out,
                                              tb_face, tb_idx, tb_w);
  } else {
    interior_kernel<<<98304, 256, 0, stream>>>((const float4*)in, out);
    const unsigned btotal = 6144u * 516u;
    border_kernel<<<(btotal + 255u) / 256u, 256, 0, stream>>>(in, out);
  }
}

// Round 16
// 231.511 us; speedup vs baseline: 1.2539x; 1.0034x over previous
//
#include <hip/hip_runtime.h>

#define H    128
#define WP   130
#define BPF  516           // border pixels per face image
#define TBLN 3096          // 6 * 516
#define NIMG 6144

typedef float f32x4  __attribute__((ext_vector_type(4)));
typedef float f32x4u __attribute__((ext_vector_type(4), aligned(4)));  // dword-aligned vec load

// Face order: back(0), down(1), front(2), left(3), right(4), top(5)
__constant__ int c_R[6][9] = {
  {-1,0,0,  0,1,0,  0,0,-1},
  { 1,0,0,  0,0,-1, 0,1,0 },
  { 1,0,0,  0,1,0,  0,0,1 },
  { 0,0,1,  0,1,0, -1,0,0 },
  { 0,0,-1, 0,1,0,  1,0,0 },
  { 1,0,0,  0,0,1,  0,-1,0},
};
// NEIGHBORS[face][side], side order: up(0), down(1), left(2), right(3)
__constant__ int c_conn[6][4] = {
  {5,1,4,3}, {2,0,3,4}, {5,1,3,4}, {5,1,0,2}, {5,1,2,0}, {0,2,3,4},
};

#define INV_FP (65.0f / 4128.0f)

// ---------- kernel A: build border table (3096 entries) ------------------
__global__ void __launch_bounds__(256)
border_table_kernel(int* __restrict__ tb_face, int4* __restrict__ tb_idx,
                    float4* __restrict__ tb_w) {
  int t = blockIdx.x * 256 + threadIdx.x;
  if (t >= TBLN) return;
  int face = t / BPF;
  int k    = t - face * BPF;

  int r, c;
  if (k < 130)      { r = 0;        c = k; }
  else if (k < 260) { r = WP - 1;   c = k - 130; }
  else if (k < 388) { r = k - 259;  c = 0; }
  else              { r = k - 387;  c = WP - 1; }

  int fs = -1;
  int4  idx = make_int4(0, 0, 0, 0);
  float4 w  = make_float4(0.f, 0.f, 0.f, 0.f);

  int cand[2]; int nc = 0;
  if (c == WP - 1) cand[nc++] = 3;
  if (c == 0)      cand[nc++] = 2;
  if (r == WP - 1) cand[nc++] = 1;
  if (r == 0)      cand[nc++] = 0;

  float uc = ((float)c - 64.5f) * INV_FP;
  float ur = ((float)r - 64.5f) * INV_FP;

  for (int kk = 0; kk < nc; ++kk) {
    int s  = cand[kk];
    int cf = c_conn[face][s];
    const int* Rc = c_R[cf];
    const int* Rf = c_R[face];
    float g[3];
    #pragma unroll
    for (int i = 0; i < 3; ++i) {
      float acc = 0.0f;
      #pragma unroll
      for (int j = 0; j < 3; ++j) {
        int rr = Rc[i*3+0]*Rf[j*3+0] + Rc[i*3+1]*Rf[j*3+1] + Rc[i*3+2]*Rf[j*3+2];
        float dj = (j == 0) ? uc : (j == 1) ? ur : 1.0f;
        acc += (float)rr * dj;
      }
      g[i] = acc;
    }
    float x = g[0] / g[2];
    float y = g[1] / g[2];
    if (fabsf(x) <= 1.01f && fabsf(y) <= 1.01f) {
      x = fminf(fmaxf(x, -1.0f), 1.0f);
      y = fminf(fmaxf(y, -1.0f), 1.0f);
      float xp = (x + 1.0f) * 0.5f * (float)(H - 1);
      float yp = (y + 1.0f) * 0.5f * (float)(H - 1);
      float x0 = floorf(xp), y0 = floorf(yp);
      float wx = xp - x0,    wy = yp - y0;
      int x0i = min(max((int)x0, 0), H - 1);
      int x1i = min(x0i + 1, H - 1);
      int y0i = min(max((int)y0, 0), H - 1);
      int y1i = min(y0i + 1, H - 1);
      fs  = cf;
      idx = make_int4(y0i * H + x0i, y0i * H + x1i, y1i * H + x0i, y1i * H + x1i);
      w   = make_float4((1.f - wx) * (1.f - wy), wx * (1.f - wy),
                        (1.f - wx) * wy,         wx * wy);
      break;
    }
  }
  tb_face[t] = fs;
  tb_idx[t]  = idx;
  tb_w[t]    = w;
}

// ---------- kernel B: fused bulk + edge, shuffle-free nt variant ---------
// R15 structure (grid (17, NIMG), 256 threads; bx==0 edge-first, bx 1..16
// bulk). Bulk now uses a DIRECT dword-aligned vector load of the output
// quad's input span (i0 = 4*qq - 2*g - 129, R6-verified algebra) instead of
// the aligned-load + 3x shfl chain: 1 load + 1 nt-store per quad, no LDS,
// no cross-lane dependency. Edge path byte-identical to R15 (verified).
__global__ void __launch_bounds__(256)
fused_nt2_kernel(const float* __restrict__ in, float* __restrict__ out,
                 const int* __restrict__ tb_face,
                 const int4* __restrict__ tb_idx,
                 const float4* __restrict__ tb_w) {
  const unsigned bx  = blockIdx.x;
  const unsigned img = blockIdx.y;
  const unsigned u   = threadIdx.x;
  f32x4* out4 = (f32x4*)out;

  if (bx != 0u) {
    // ---- bulk path (shuffle-free) ----
    unsigned hh = ((bx - 1u) << 3) + (u >> 5); // half index 0..127
    unsigned l  = u & 31u;                     // lane in 32-group
    unsigned g  = hh + 1u;                     // output row 1..128
    unsigned m  = g >> 1;                      // row-pair 0..64
    unsigned h  = g & 1u;                      // 1 = odd row of pair

    if (l < 31u) {
      unsigned qq = 65u * m + 1u + (h << 5) + l;      // output quad in image
      unsigned i0 = (qq << 2) - (g << 1) - 129u;      // input elem offset
      const f32x4u* src =
          (const f32x4u*)(in + ((size_t)img << 14) + i0);
      f32x4u A = __builtin_nontemporal_load(src);
      f32x4 o; o.x = A.x; o.y = A.y; o.z = A.z; o.w = A.w;
      __builtin_nontemporal_store(o, &out4[(size_t)img * 4225u + qq]);
    }
  } else {
    // ---- edge path: 257 quads for this image ----
    unsigned n    = img >> 8;
    unsigned ch   = img & 255u;
    unsigned rep  = n / 6u;
    unsigned face = n - rep * 6u;

    for (unsigned k = u; k < 257u; k += 256u) {
      unsigned qk;
      if (k < 33u)       qk = k;                     // pair 0: q 0..32
      else if (k == 33u) qk = 64u;                   // pair 0: q 64
      else if (k == 34u) qk = 4160u;                 // pair 64: q 0
      else if (k < 68u)  qk = 4192u + (k - 35u);     // pair 64: q 32..64
      else {
        unsigned jj = k - 68u;                       // 0..188
        unsigned mm = 1u + jj / 3u;                  // 1..63
        unsigned w  = jj - 3u * (jj / 3u);           // 0,1,2
        qk = 65u * mm + ((w == 0u) ? 0u : (w == 1u) ? 32u : 64u);
      }

      unsigned p = qk << 2;
      unsigned r = p / 130u;
      unsigned c = p - r * 130u;
      float vals[4];
      #pragma unroll
      for (int e = 0; e < 4; ++e) {
        float v;
        if ((r - 1u) < 128u && (c - 1u) < 128u) {
          v = in[((size_t)img << 14) + ((r - 1u) << 7) + (c - 1u)];
        } else {
          unsigned tk = (r == 0u)   ? c
                      : (r == 129u) ? (130u + c)
                      : (c == 0u)   ? (259u + r)
                      :               (387u + r);
          unsigned ti = face * (unsigned)BPF + tk;
          int fs = tb_face[ti];
          v = 0.0f;
          if (fs >= 0) {
            int4   id = tb_idx[ti];
            float4 w  = tb_w[ti];
            const float* s = in +
                ((size_t)(((rep * 6u + (unsigned)fs) << 8) + ch) << 14);
            v = w.x * s[id.x] + w.y * s[id.y] + w.z * s[id.z] + w.w * s[id.w];
          }
        }
        vals[e] = v;
        if (++c == 130u) { c = 0u; ++r; }
      }
      f32x4 ov; ov.x = vals[0]; ov.y = vals[1]; ov.z = vals[2]; ov.w = vals[3];
      __builtin_nontemporal_store(ov, &out4[(size_t)img * 4225u + qk]);
    }
  }
}

// ---------- fallback: round-2 simple kernels ------------------------------
__global__ void __launch_bounds__(256)
interior_kernel(const float4* __restrict__ in4, float* __restrict__ out) {
  unsigned t = blockIdx.x * 256u + threadIdx.x;
  unsigned c4  = t & 31u;
  unsigned r   = (t >> 5) & 127u;
  unsigned img = t >> 12;
  float4 v = in4[t];
  unsigned o = img * 16900u + (r + 1u) * 130u + 1u + (c4 << 2);
  out[o] = v.x; out[o + 1] = v.y; out[o + 2] = v.z; out[o + 3] = v.w;
}

__global__ void __launch_bounds__(256)
border_kernel(const float* __restrict__ in, float* __restrict__ out) {
  unsigned tid = blockIdx.x * 256u + threadIdx.x;
  const unsigned total = 6144u * 516u;
  if (tid >= total) return;
  unsigned img = tid / 516u;
  unsigned k   = tid - img * 516u;
  int r, c;
  if (k < 130u)      { r = 0;               c = (int)k; }
  else if (k < 260u) { r = WP - 1;          c = (int)(k - 130u); }
  else if (k < 388u) { r = (int)(k - 259u); c = 0; }
  else               { r = (int)(k - 387u); c = WP - 1; }
  int n = (int)(img >> 8), ch = (int)(img & 255u);
  int face = n % 6, rep = n / 6;
  float v = 0.0f;
  int cand[2]; int nc = 0;
  if (c == WP - 1) cand[nc++] = 3;
  if (c == 0)      cand[nc++] = 2;
  if (r == WP - 1) cand[nc++] = 1;
  if (r == 0)      cand[nc++] = 0;
  float uc = ((float)c - 64.5f) * INV_FP;
  float ur = ((float)r - 64.5f) * INV_FP;
  for (int kk = 0; kk < nc; ++kk) {
    int s = cand[kk], cf = c_conn[face][s];
    const int* Rc = c_R[cf]; const int* Rf = c_R[face];
    float g[3];
    #pragma unroll
    for (int i = 0; i < 3; ++i) {
      float acc = 0.0f;
      #pragma unroll
      for (int j = 0; j < 3; ++j) {
        int rr = Rc[i*3+0]*Rf[j*3+0] + Rc[i*3+1]*Rf[j*3+1] + Rc[i*3+2]*Rf[j*3+2];
        float dj = (j == 0) ? uc : (j == 1) ? ur : 1.0f;
        acc += (float)rr * dj;
      }
      g[i] = acc;
    }
    float x = g[0] / g[2], y = g[1] / g[2];
    if (fabsf(x) <= 1.01f && fabsf(y) <= 1.01f) {
      x = fminf(fmaxf(x, -1.0f), 1.0f);
      y = fminf(fmaxf(y, -1.0f), 1.0f);
      const float* src = in + ((size_t)((rep * 6 + cf) * 256 + ch)) * H * H;
      float xp = (x + 1.0f) * 0.5f * (float)(H - 1);
      float yp = (y + 1.0f) * 0.5f * (float)(H - 1);
      float x0 = floorf(xp), y0 = floorf(yp);
      float wx = xp - x0, wy = yp - y0;
      int x0i = min(max((int)x0, 0), H - 1);
      int x1i = min(x0i + 1, H - 1);
      int y0i = min(max((int)y0, 0), H - 1);
      int y1i = min(y0i + 1, H - 1);
      v = src[y0i*H+x0i]*(1.f-wx)*(1.f-wy) + src[y0i*H+x1i]*wx*(1.f-wy)
        + src[y1i*H+x0i]*(1.f-wx)*wy       + src[y1i*H+x1i]*wx*wy;
      break;
    }
  }
  out[(unsigned)img * 16900u + (unsigned)r * 130u + (unsigned)c] = v;
}

extern "C" void kernel_launch(void* const* d_in, const int* in_sizes, int n_in,
                              void* d_out, int out_size, void* d_ws, size_t ws_size,
                              hipStream_t stream) {
  (void)in_sizes; (void)n_in; (void)out_size;
  const float* in = (const float*)d_in[0];
  float* out = (float*)d_out;

  const size_t tbl_bytes = (size_t)TBLN * (4 + 16 + 16);   // 111,456 B

  if (d_ws != nullptr && ws_size >= tbl_bytes) {
    int*    tb_face = (int*)d_ws;
    int4*   tb_idx  = (int4*)(tb_face + TBLN);
    float4* tb_w    = (float4*)(tb_idx + TBLN);
    border_table_kernel<<<(TBLN + 255) / 256, 256, 0, stream>>>(
        tb_face, tb_idx, tb_w);

    dim3 grid(17, NIMG);   // x==0 edge (first), x 1..16 bulk
    fused_nt2_kernel<<<grid, 256, 0, stream>>>(in, out,
                                               tb_face, tb_idx, tb_w);
  } else {
    interior_kernel<<<98304, 256, 0, stream>>>((const float4*)in, out);
    const unsigned btotal = 6144u * 516u;
    border_kernel<<<(btotal + 255u) / 256u, 256, 0, stream>>>(in, out);
  }
}